// Round 1
// baseline (78.909 us; speedup 1.0000x reference)
//
#include <hip/hip_runtime.h>

// DNM dendritic layer: out[b,o] = max(0, 0.25*S - 0.05),
//   S = sum_{m,i} relu(x[b,i]*W[o,m,i] - q[o,m,i])
// B=512, OUT=128, M=8, IN=512, fp32 in/out.
//
// R12: two-kernel pipeline. Theory: ~25% of issue slots and 384 MB of L2
// traffic were redundant f32->f16 conversion/staging repeated per block
// (W/q x32, x x128). Pre-pass converts x,W,q to fp16 into d_ws once
// (~2us, memory-bound); main kernel tiles 2 o x 32 b per block
// (1024 blocks, 32 KB LDS, single resident generation), stages W/q via
// global_load_lds width-16 (zero staging VALU), loads x as h8 directly,
// 8 b/thread (0.5 B LDS per element). Core stays 1.5 pk-fp16 VALU/elem
// (the ~8us floor); per-m h2 partial sums (3 pk_add) + one fdot2 cut
// dot2 usage 4x. L2 reads 384->64 MB.

#define OUTN 128
#define MM   8
#define INN  512
#define BB   512

typedef float    f4 __attribute__((ext_vector_type(4)));
typedef _Float16 h2 __attribute__((ext_vector_type(2)));
typedef _Float16 h4 __attribute__((ext_vector_type(4)));
typedef _Float16 h8 __attribute__((ext_vector_type(8)));

// d_ws layout in _Float16 units:
#define XH 0
#define WH (BB * INN)               // 262144
#define QH (WH + OUTN * MM * INN)   // 786432

// ---------------- pre-pass: f32 -> fp16 (RNE) into workspace ----------------
// 160K h8-groups total: x 32K, W 64K, q 64K. Grid 640 x 256, exact.
__global__ __launch_bounds__(256) void cvt_fp16(
    const float* __restrict__ x, const float* __restrict__ W,
    const float* __restrict__ q, _Float16* __restrict__ ws)
{
    const int j  = blockIdx.x * 256 + threadIdx.x;
    const int NX = BB * INN / 8;          // 32768
    const int NW = OUTN * MM * INN / 8;   // 65536

    const float* src;
    _Float16*    dst;
    int k;
    if (j < NX)           { src = x; dst = ws + XH; k = j; }
    else if (j < NX + NW) { src = W; dst = ws + WH; k = j - NX; }
    else                  { src = q; dst = ws + QH; k = j - NX - NW; }

    f4 a = ((const f4*)src)[2 * k];
    f4 b = ((const f4*)src)[2 * k + 1];
    h4 lo = __builtin_convertvector(a, h4);   // RNE
    h4 hi = __builtin_convertvector(b, h4);   // RNE
    *(h8*)(dst + (size_t)k * 8) = __builtin_shufflevector(lo, hi, 0, 1, 2, 3, 4, 5, 6, 7);
}

// ---------------- main kernel ----------------
__device__ __forceinline__ void gload_lds16(const _Float16* g, _Float16* l)
{
#if __has_builtin(__builtin_amdgcn_global_load_lds)
    __builtin_amdgcn_global_load_lds(
        (const __attribute__((address_space(1))) unsigned int*)g,
        (__attribute__((address_space(3))) unsigned int*)l, 16, 0, 0);
#else
    *(h8*)l = *(const h8*)g;   // fallback: reg round-trip copy
#endif
}

// Block: 256 threads = 4 waves. Tile: 2 o's x 32 b's (8 b per wave,
// 8 b x 2 o = 16 f32 accumulators per thread). Lane owns i0 = lane*8.
// Grid: 64 o-groups x 16 b-groups = 1024 blocks = 4/CU, one generation.
// LDS: 32 KB (W + q for 2 o's, fp16).
__global__ __launch_bounds__(256) void dnm_main(
    const _Float16* __restrict__ ws, float* __restrict__ out)
{
    __shared__ _Float16 lw[2 * MM * INN];   // 16 KB
    __shared__ _Float16 lq[2 * MM * INN];   // 16 KB

    const int tid  = threadIdx.x;
    const int og   = blockIdx.x >> 4;    // 0..63
    const int bgrp = blockIdx.x & 15;    // 0..15
    const int wave = tid >> 6;
    const int lane = tid & 63;
    const int o0   = og * 2;
    const int b0   = bgrp * 32 + wave * 8;
    const int i0   = lane * 8;

    // Stage W[o0..o0+1], q[o0..o0+1] (8192 halfs each) via global_load_lds.
    // Per round: 4 waves x 1 KB = 4 KB; 4 rounds each for W and q.
    {
        const _Float16* gw = ws + WH + (size_t)o0 * (MM * INN);
        const _Float16* gq = ws + QH + (size_t)o0 * (MM * INN);
        #pragma unroll
        for (int r = 0; r < 4; ++r) {
            const int h_off = r * 2048 + wave * 512;   // wave-uniform (h units)
            gload_lds16(gw + h_off + lane * 8, lw + h_off);
            gload_lds16(gq + h_off + lane * 8, lq + h_off);
        }
    }

    // This wave's 8 x-rows, fp16 direct from workspace (no converts).
    h8 xv[8];
    {
        const _Float16* xb = ws + XH + (size_t)b0 * INN + i0;
        #pragma unroll
        for (int b = 0; b < 8; ++b) xv[b] = *(const h8*)(xb + (size_t)b * INN);
    }

    __syncthreads();   // drains vmcnt(0): global_load_lds complete

    float acc[8][2];
    #pragma unroll
    for (int b = 0; b < 8; ++b) {
        acc[b][0] = 0.0f;
        acc[b][1] = 0.0f;
    }

    const h2 one  = {(_Float16)1.0f, (_Float16)1.0f};
    const h2 zero = (h2)(_Float16)0.0f;

    #pragma unroll 2
    for (int m = 0; m < MM; ++m) {
        h8 w8[2], q8[2];
        #pragma unroll
        for (int o = 0; o < 2; ++o) {
            w8[o] = *(const h8*)(lw + o * (MM * INN) + m * INN + i0);
            q8[o] = *(const h8*)(lq + o * (MM * INN) + m * INN + i0);
        }
        #pragma unroll
        for (int b = 0; b < 8; ++b) {
            #pragma unroll
            for (int o = 0; o < 2; ++o) {
                // per p: v_pk_fma_f16 + v_pk_max_f16; then 3 v_pk_add_f16
                // + 1 v_dot2_f32_f16 (per-m h2 partial sum keeps fp16
                // rounding bounded to 8-element groups).
                h2 t0, t1, t2, t3;
                {
                    h2 xx = __builtin_shufflevector(xv[b], xv[b], 0, 1);
                    h2 ww = __builtin_shufflevector(w8[o], w8[o], 0, 1);
                    h2 qq = __builtin_shufflevector(q8[o], q8[o], 0, 1);
                    t0 = __builtin_elementwise_max(__builtin_elementwise_fma(xx, ww, -qq), zero);
                }
                {
                    h2 xx = __builtin_shufflevector(xv[b], xv[b], 2, 3);
                    h2 ww = __builtin_shufflevector(w8[o], w8[o], 2, 3);
                    h2 qq = __builtin_shufflevector(q8[o], q8[o], 2, 3);
                    t1 = __builtin_elementwise_max(__builtin_elementwise_fma(xx, ww, -qq), zero);
                }
                {
                    h2 xx = __builtin_shufflevector(xv[b], xv[b], 4, 5);
                    h2 ww = __builtin_shufflevector(w8[o], w8[o], 4, 5);
                    h2 qq = __builtin_shufflevector(q8[o], q8[o], 4, 5);
                    t2 = __builtin_elementwise_max(__builtin_elementwise_fma(xx, ww, -qq), zero);
                }
                {
                    h2 xx = __builtin_shufflevector(xv[b], xv[b], 6, 7);
                    h2 ww = __builtin_shufflevector(w8[o], w8[o], 6, 7);
                    h2 qq = __builtin_shufflevector(q8[o], q8[o], 6, 7);
                    t3 = __builtin_elementwise_max(__builtin_elementwise_fma(xx, ww, -qq), zero);
                }
                h2 s = (t0 + t1) + (t2 + t3);
#if __has_builtin(__builtin_amdgcn_fdot2)
                acc[b][o] = __builtin_amdgcn_fdot2(s, one, acc[b][o], false);
#else
                acc[b][o] += (float)s[0] + (float)s[1];
#endif
            }
        }
    }

    // Butterfly-reduce each of the 16 accs across 64 lanes; lane b*2+o writes.
    #pragma unroll
    for (int b = 0; b < 8; ++b) {
        #pragma unroll
        for (int o = 0; o < 2; ++o) {
            float v = acc[b][o];
            v += __shfl_xor(v, 1, 64);
            v += __shfl_xor(v, 2, 64);
            v += __shfl_xor(v, 4, 64);
            v += __shfl_xor(v, 8, 64);
            v += __shfl_xor(v, 16, 64);
            v += __shfl_xor(v, 32, 64);
            if (lane == (b * 2 + o)) {
                float r = 0.25f * v - 0.05f;   // K*K*S - K*QS
                out[(size_t)(b0 + b) * OUTN + (o0 + o)] = fmaxf(r, 0.0f);
            }
        }
    }
}

extern "C" void kernel_launch(void* const* d_in, const int* in_sizes, int n_in,
                              void* d_out, int out_size, void* d_ws, size_t ws_size,
                              hipStream_t stream)
{
    const float* x = (const float*)d_in[0];
    const float* W = (const float*)d_in[1];
    const float* q = (const float*)d_in[2];
    float* out = (float*)d_out;
    _Float16* ws = (_Float16*)d_ws;   // needs 2.62 MB; ws is 256 MB (fill evidence)

    // 160K h8-groups / 256 = 640 blocks, exact.
    cvt_fp16<<<dim3(640), dim3(256), 0, stream>>>(x, W, q, ws);
    // 64 o-groups x 16 b-groups = 1024 blocks.
    dnm_main<<<dim3(1024), dim3(256), 0, stream>>>(ws, out);
}